// Round 2
// baseline (237.472 us; speedup 1.0000x reference)
//
#include <hip/hip_runtime.h>

// Interface (pinned): inputs fp32, mask int32, OUTPUT fp32.
// R11 = R10 with attention rebuilt as a BARRIER-FREE kernel:
//   R10 post-mortem: LDS pipe saturated (~98K of 110K CU-cycles were LDS
//   issue: K/V stage writes + 4x-redundant per-wave fragment reads).
//   - K and V MFMA fragments now load DIRECTLY global->VGPR (same per-lane
//     addresses the LDS reads used; bit-identical values; 64B-segment
//     coalesced; L1/L2-resident: 16KB tile, 256KB per (b,h), XCD-grouped).
//   - No K/V LDS staging => no __syncthreads anywhere. Only the verified
//     per-wave RNE-bf16 P-through-LDS path remains (in-wave RAW,
//     program-ordered).
//   - mask bias computed inline from global int mask (same 0/-30000 values).
//   - wave = 32 q-rows (2 m-tiles), block = 2 waves, grid 1024,
//     __launch_bounds__(128,3) => ~12 waves/CU, LDS 11KB/block.
// GEMMs/LNs/transposes and WS layout identical to R10.

typedef float f32x4 __attribute__((ext_vector_type(4)));
typedef short bf16x8 __attribute__((ext_vector_type(8)));
typedef unsigned short u16;

#define MFMA16 __builtin_amdgcn_mfma_f32_16x16x32_bf16

__device__ __forceinline__ float bf2f(u16 u){
    unsigned x = ((unsigned)u) << 16;
    return __builtin_bit_cast(float, x);
}
__device__ __forceinline__ u16 f2bf(float f){  // round-to-nearest-even
    unsigned u = __builtin_bit_cast(unsigned, f);
    u = u + 0x7fffu + ((u >> 16) & 1u);
    return (u16)(u >> 16);
}

// ---------------------------------------------------------------------------
// Transpose + fp32->bf16 the 4 weight matrices (512x512).
// ---------------------------------------------------------------------------
__global__ __launch_bounds__(256) void transpose_w(
    const float* __restrict__ Wq, const float* __restrict__ Wk,
    const float* __restrict__ Wv, const float* __restrict__ Wo,
    u16* __restrict__ wt)
{
    const int z = blockIdx.z;
    const float* W = (z == 0) ? Wq : (z == 1) ? Wk : (z == 2) ? Wv : Wo;
    u16* out = wt + (size_t)z * 512 * 512;

    __shared__ u16 tile[32][33];
    const int k0 = blockIdx.y * 32, n0 = blockIdx.x * 32;
    const int c = threadIdx.x & 31, r = threadIdx.x >> 5;
#pragma unroll
    for (int i = 0; i < 4; i++) {
        int rr = r + i * 8;
        tile[rr][c] = f2bf(W[(size_t)(k0 + rr) * 512 + n0 + c]);
    }
    __syncthreads();
#pragma unroll
    for (int i = 0; i < 4; i++) {
        int rr = r + i * 8;
        out[(size_t)(n0 + rr) * 512 + k0 + c] = tile[c][rr];
    }
}

// ---------------------------------------------------------------------------
// Transpose V: vb[8192][512] (bf16) -> vtg[(b*8+h)*64 + d][1024 keys] (bf16).
// ---------------------------------------------------------------------------
__global__ __launch_bounds__(256) void transpose_v(
    const u16* __restrict__ vb, u16* __restrict__ vtg)
{
    __shared__ u16 tile[32][33];
    const int bh = blockIdx.z;              // 0..63
    const int b = bh >> 3, h = bh & 7;
    const int k0 = blockIdx.x * 32, d0 = blockIdx.y * 32;
    const int c = threadIdx.x & 31, r = threadIdx.x >> 5;
#pragma unroll
    for (int i = 0; i < 4; i++) {
        int rr = r + i * 8;
        tile[rr][c] = vb[(size_t)(b * 1024 + k0 + rr) * 512 + h * 64 + d0 + c];
    }
    __syncthreads();
#pragma unroll
    for (int i = 0; i < 4; i++) {
        int rr = r + i * 8;
        vtg[(size_t)(bh * 64 + d0 + rr) * 1024 + k0 + c] = tile[c][rr];
    }
}

// ---------------------------------------------------------------------------
// Projection GEMM (verified R5): C = X(fp32) @ W(bf16^T) + bias -> bf16.
// ---------------------------------------------------------------------------
__global__ __launch_bounds__(256) void gemm_proj(
    const float* __restrict__ Q, const float* __restrict__ K,
    const u16* __restrict__ wt,
    const float* __restrict__ bq, const float* __restrict__ bk, const float* __restrict__ bv,
    u16* __restrict__ qb, u16* __restrict__ kb, u16* __restrict__ vb)
{
    __shared__ __align__(16) u16 lds_a[128 * 40];
    __shared__ __align__(16) u16 lds_b[128 * 40];

    const int z = blockIdx.z;
    const float* X = (z == 0) ? Q : K;
    const u16* Wt = wt + (size_t)z * 512 * 512;
    const float* bias = (z == 0) ? bq : (z == 1) ? bk : bv;
    u16* outb = (z == 0) ? qb : (z == 1) ? kb : vb;

    const int bm = blockIdx.y, bn = blockIdx.x;
    const int t = threadIdx.x;
    const int wave = t >> 6, lane = t & 63, quad = lane >> 4, lm = lane & 15;
    const int wm = wave >> 1, wn = wave & 1;

    f32x4 acc[4][4];
    const f32x4 zz = {0.f, 0.f, 0.f, 0.f};
#pragma unroll
    for (int i = 0; i < 4; i++)
#pragma unroll
        for (int j = 0; j < 4; j++) acc[i][j] = zz;

    for (int k0 = 0; k0 < 512; k0 += 32) {
#pragma unroll
        for (int i = 0; i < 2; i++) {
            int idx = t + i * 256;
            int r = idx >> 2, c = (idx & 3) * 8;
            const float* xp = &X[(size_t)(bm * 128 + r) * 512 + k0 + c];
            f32x4 a0 = *(const f32x4*)xp;
            f32x4 a1 = *(const f32x4*)(xp + 4);
            bf16x8 xv;
#pragma unroll
            for (int j = 0; j < 4; j++) { xv[j] = (short)f2bf(a0[j]); xv[4 + j] = (short)f2bf(a1[j]); }
            *(bf16x8*)&lds_a[r * 40 + c] = xv;
            *(bf16x8*)&lds_b[r * 40 + c] =
                *(const bf16x8*)&Wt[(size_t)(bn * 128 + r) * 512 + k0 + c];
        }
        __syncthreads();
        bf16x8 af[4], bfr[4];
#pragma unroll
        for (int mi = 0; mi < 4; mi++)
            af[mi] = *(const bf16x8*)&lds_a[(wm * 64 + mi * 16 + lm) * 40 + quad * 8];
#pragma unroll
        for (int ni = 0; ni < 4; ni++)
            bfr[ni] = *(const bf16x8*)&lds_b[(wn * 64 + ni * 16 + lm) * 40 + quad * 8];
#pragma unroll
        for (int mi = 0; mi < 4; mi++)
#pragma unroll
            for (int ni = 0; ni < 4; ni++)
                acc[mi][ni] = MFMA16(af[mi], bfr[ni], acc[mi][ni], 0, 0, 0);
        __syncthreads();
    }

#pragma unroll
    for (int mi = 0; mi < 4; mi++) {
#pragma unroll
        for (int ni = 0; ni < 4; ni++) {
            const int col = bn * 128 + wn * 64 + ni * 16 + lm;
            const float bv_ = bias[col];
#pragma unroll
            for (int r = 0; r < 4; r++) {
                const int row = bm * 128 + wm * 64 + mi * 16 + quad * 4 + r;
                outb[(size_t)row * 512 + col] = f2bf(acc[mi][ni][r] + bv_);
            }
        }
    }
}

// ---------------------------------------------------------------------------
// MLP GEMM (verified R5): Uf = resid(fp32) + relu(X(bf16) @ Wo^T + bo) -> fp32.
// ---------------------------------------------------------------------------
__global__ __launch_bounds__(256) void gemm_mlp(
    const u16* __restrict__ X, const u16* __restrict__ wt,
    const float* __restrict__ bo, const float* __restrict__ resid,
    float* __restrict__ outf)
{
    __shared__ __align__(16) u16 lds_a[128 * 40];
    __shared__ __align__(16) u16 lds_b[128 * 40];

    const u16* Wt = wt + (size_t)3 * 512 * 512;
    const int bm = blockIdx.y, bn = blockIdx.x;
    const int t = threadIdx.x;
    const int wave = t >> 6, lane = t & 63, quad = lane >> 4, lm = lane & 15;
    const int wm = wave >> 1, wn = wave & 1;

    f32x4 acc[4][4];
    const f32x4 zz = {0.f, 0.f, 0.f, 0.f};
#pragma unroll
    for (int i = 0; i < 4; i++)
#pragma unroll
        for (int j = 0; j < 4; j++) acc[i][j] = zz;

    for (int k0 = 0; k0 < 512; k0 += 32) {
#pragma unroll
        for (int i = 0; i < 2; i++) {
            int idx = t + i * 256;
            int r = idx >> 2, c = (idx & 3) * 8;
            *(bf16x8*)&lds_a[r * 40 + c] =
                *(const bf16x8*)&X[(size_t)(bm * 128 + r) * 512 + k0 + c];
            *(bf16x8*)&lds_b[r * 40 + c] =
                *(const bf16x8*)&Wt[(size_t)(bn * 128 + r) * 512 + k0 + c];
        }
        __syncthreads();
        bf16x8 af[4], bfr[4];
#pragma unroll
        for (int mi = 0; mi < 4; mi++)
            af[mi] = *(const bf16x8*)&lds_a[(wm * 64 + mi * 16 + lm) * 40 + quad * 8];
#pragma unroll
        for (int ni = 0; ni < 4; ni++)
            bfr[ni] = *(const bf16x8*)&lds_b[(wn * 64 + ni * 16 + lm) * 40 + quad * 8];
#pragma unroll
        for (int mi = 0; mi < 4; mi++)
#pragma unroll
            for (int ni = 0; ni < 4; ni++)
                acc[mi][ni] = MFMA16(af[mi], bfr[ni], acc[mi][ni], 0, 0, 0);
        __syncthreads();
    }

#pragma unroll
    for (int mi = 0; mi < 4; mi++) {
#pragma unroll
        for (int ni = 0; ni < 4; ni++) {
            const int col = bn * 128 + wn * 64 + ni * 16 + lm;
            const float bv_ = bo[col];
#pragma unroll
            for (int r = 0; r < 4; r++) {
                const int row = bm * 128 + wm * 64 + mi * 16 + quad * 4 + r;
                const size_t off = (size_t)row * 512 + col;
                outf[off] = resid[off] + fmaxf(acc[mi][ni][r] + bv_, 0.f);
            }
        }
    }
}

// ---------------------------------------------------------------------------
// Attention v5: BARRIER-FREE. Block = 2 waves, each wave owns 32 q-rows
// (2 m-tiles) of one (b,h). Grid 1024 (64 bh x 16 q-tiles of 64 rows).
// K/V MFMA fragments load directly global->VGPR (L1/L2-resident tiles;
// same per-lane addresses as the old LDS reads => bit-identical values).
// P stays on the R8-verified per-wave RNE-bf16-through-LDS path (in-wave
// RAW, program-ordered, no barrier). Mask bias (0/-30000) computed inline.
// XCD swizzle groups all 16 q-tiles of a (b,h) on one XCD's L2.
// ---------------------------------------------------------------------------
__global__ __launch_bounds__(128, 3) void attn_kernel(
    const u16* __restrict__ qb, const u16* __restrict__ kb, const u16* __restrict__ vtg,
    const int* __restrict__ mask, float* __restrict__ O)
{
    __shared__ __align__(16) u16 p_st[2 * 32 * 88];     // per-wave [qrow][key]

    const int i = blockIdx.x;
    const int s_ = i >> 3;
    const int bh = (i & 7) + 8 * (s_ >> 4);
    const int qt = s_ & 15;
    const int b = bh >> 3, h = bh & 7;

    const int t = threadIdx.x, wave = t >> 6, lane = t & 63;
    const int quad = lane >> 4, lm = lane & 15;
    const int qbase = qt * 64 + wave * 32;
    const size_t baseb = (size_t)b * 1024 * 512;
    const size_t vbase = (size_t)((b * 8 + h) * 64) * 1024;
    const int* mrow = &mask[b * 1024];

    // Q A-frags: 2 m-tiles x 2 d-halves
    bf16x8 aq[2][2];
#pragma unroll
    for (int m = 0; m < 2; m++)
#pragma unroll
        for (int ks = 0; ks < 2; ks++)
            aq[m][ks] = *(const bf16x8*)&qb[baseb +
                (size_t)(qbase + m * 16 + lm) * 512 + h * 64 + ks * 32 + quad * 8];

    float lsum[2][4];
    f32x4 oacc[2][4];
    const f32x4 zz = {0.f, 0.f, 0.f, 0.f};
#pragma unroll
    for (int m = 0; m < 2; m++) {
#pragma unroll
        for (int r = 0; r < 4; r++) lsum[m][r] = 0.f;
#pragma unroll
        for (int c = 0; c < 4; c++) oacc[m][c] = zz;
    }

    const float SC2 = 0.125f * 1.44269504088896341f; // (1/sqrt(64)) * log2(e)
    u16* pw = &p_st[wave * 32 * 88];

    for (int kt = 0; kt < 16; ++kt) {
        const int keyg = kt * 64;

        // K fragments direct from global (B-frag of QK^T): [n][ks]
        bf16x8 bkf[4][2];
#pragma unroll
        for (int n = 0; n < 4; n++)
#pragma unroll
            for (int ks = 0; ks < 2; ks++)
                bkf[n][ks] = *(const bf16x8*)&kb[baseb +
                    (size_t)(keyg + n * 16 + lm) * 512 + h * 64 + ks * 32 + quad * 8];

        // V^T fragments direct from global (B-frag of PV): [c][ks]
        bf16x8 bvf[4][2];
#pragma unroll
        for (int c = 0; c < 4; c++)
#pragma unroll
            for (int ks = 0; ks < 2; ks++)
                bvf[c][ks] = *(const bf16x8*)&vtg[vbase +
                    (size_t)(c * 16 + lm) * 1024 + keyg + ks * 32 + quad * 8];

        // mask bias per n-tile (0 or -30000, same values as R10's mbias)
        float bias[4];
#pragma unroll
        for (int n = 0; n < 4; n++)
            bias[n] = mrow[keyg + n * 16 + lm] ? 0.0f : -30000.0f;

        // QK^T + softmax numerator -> P (bf16, per-wave LDS)
#pragma unroll
        for (int m = 0; m < 2; m++) {
#pragma unroll
            for (int n = 0; n < 4; n++) {
                f32x4 S = zz;
                __builtin_amdgcn_s_setprio(1);
                S = MFMA16(aq[m][0], bkf[n][0], S, 0, 0, 0);
                S = MFMA16(aq[m][1], bkf[n][1], S, 0, 0, 0);
                __builtin_amdgcn_s_setprio(0);
#pragma unroll
                for (int r = 0; r < 4; r++) {
                    float p = __builtin_amdgcn_exp2f(__builtin_fmaf(S[r], SC2, bias[n]));
                    lsum[m][r] += p;
                    pw[(m * 16 + quad * 4 + r) * 88 + n * 16 + lm] = f2bf(p);
                }
            }
        }
        // no barrier: pw is per-wave; in-wave LDS RAW is program-ordered.

        // PV: O += P.V^T
#pragma unroll
        for (int m = 0; m < 2; m++) {
#pragma unroll
            for (int ks = 0; ks < 2; ks++) {
                bf16x8 ap = *(const bf16x8*)&pw[(m * 16 + lm) * 88 + ks * 32 + quad * 8];
                __builtin_amdgcn_s_setprio(1);
#pragma unroll
                for (int c = 0; c < 4; c++)
                    oacc[m][c] = MFMA16(ap, bvf[c][ks], oacc[m][c], 0, 0, 0);
                __builtin_amdgcn_s_setprio(0);
            }
        }
    }

    // reduce lsum across the 16 key-columns (lanes lm within each quad)
#pragma unroll
    for (int m = 0; m < 2; m++)
#pragma unroll
        for (int r = 0; r < 4; r++) {
            float s = lsum[m][r];
            s += __shfl_xor(s, 1); s += __shfl_xor(s, 2);
            s += __shfl_xor(s, 4); s += __shfl_xor(s, 8);
            lsum[m][r] = s;
        }

    // epilogue: O = q + P.V / l  (fp32, coalesced over lm)
#pragma unroll
    for (int m = 0; m < 2; m++)
#pragma unroll
        for (int c = 0; c < 4; c++)
#pragma unroll
            for (int r = 0; r < 4; r++) {
                const int row = qbase + m * 16 + quad * 4 + r;
                const int d = h * 64 + c * 16 + lm;
                const size_t off = baseb + (size_t)row * 512 + d;
                O[off] = bf2f(qb[off]) + oacc[m][c][r] / lsum[m][r];
            }
}

// ---------------------------------------------------------------------------
// Row LayerNorm over 512 (verified R5): fp32 in; optional bf16 + fp32 outs.
// ---------------------------------------------------------------------------
__global__ __launch_bounds__(256) void ln_kernel(
    const float* __restrict__ in, const float* __restrict__ g, const float* __restrict__ bsh,
    u16* __restrict__ outb, float* __restrict__ outf)
{
    const int row = blockIdx.x * 4 + (threadIdx.x >> 6);
    const int lane = threadIdx.x & 63;
    const float* x = in + (size_t)row * 512 + lane * 8;
    float v[8];
    *(f32x4*)&v[0] = *(const f32x4*)&x[0];
    *(f32x4*)&v[4] = *(const f32x4*)&x[4];
    float s = 0.f, sq = 0.f;
#pragma unroll
    for (int j = 0; j < 8; j++) { s += v[j]; sq += v[j] * v[j]; }
#pragma unroll
    for (int off = 1; off < 64; off <<= 1) {
        s += __shfl_xor(s, off);
        sq += __shfl_xor(sq, off);
    }
    const float mu = s * (1.f / 512.f);
    const float var = sq * (1.f / 512.f) - mu * mu;
    const float rs = rsqrtf(var + 1e-5f);
    float y[8];
#pragma unroll
    for (int j = 0; j < 8; j++) {
        int col = lane * 8 + j;
        y[j] = (v[j] - mu) * rs * g[col] + bsh[col];
    }
    if (outb != nullptr) {
        bf16x8 ov;
#pragma unroll
        for (int j = 0; j < 8; j++) ov[j] = (short)f2bf(y[j]);
        *(bf16x8*)&outb[(size_t)row * 512 + lane * 8] = ov;
    }
    if (outf != nullptr) {
        float* o = outf + (size_t)row * 512 + lane * 8;
        *(f32x4*)&o[0] = *(const f32x4*)&y[0];
        *(f32x4*)&o[4] = *(const f32x4*)&y[4];
    }
}

extern "C" void kernel_launch(void* const* d_in, const int* in_sizes, int n_in,
                              void* d_out, int out_size, void* d_ws, size_t ws_size,
                              hipStream_t stream) {
    const float* Q  = (const float*)d_in[0];
    const float* K  = (const float*)d_in[1];
    const int* mask = (const int*)d_in[2];
    const float* Wq = (const float*)d_in[3];
    const float* bq = (const float*)d_in[4];
    const float* Wk = (const float*)d_in[5];
    const float* bk = (const float*)d_in[6];
    const float* Wv = (const float*)d_in[7];
    const float* bv = (const float*)d_in[8];
    const float* Wo = (const float*)d_in[9];
    const float* bo = (const float*)d_in[10];
    const float* g0 = (const float*)d_in[11];
    const float* b0 = (const float*)d_in[12];
    const float* g1 = (const float*)d_in[13];
    const float* b1 = (const float*)d_in[14];
    float* out = (float*)d_out;

    char* ws = (char*)d_ws;
    const size_t MB = 1048576;
    u16*   wt  = (u16*)(ws);
    u16*   qb  = (u16*)(ws + 2 * MB);
    u16*   kb  = (u16*)(ws + 10 * MB);
    u16*   vtg = (u16*)(ws + 18 * MB);
    u16*   vb  = (u16*)(ws + 26 * MB);
    float* Of  = (float*)(ws + 26 * MB);  // overwrites vb (dead after transpose_v)
    u16*   O1b = (u16*)(ws + 2 * MB);     // reuse qb
    float* O1f = (float*)(ws + 10 * MB);  // reuse kb+vtg
    float* Uf  = (float*)(ws + 26 * MB);  // reuse Of

    transpose_w<<<dim3(16, 16, 4), 256, 0, stream>>>(Wq, Wk, Wv, Wo, wt);
    gemm_proj<<<dim3(4, 64, 3), 256, 0, stream>>>(Q, K, wt, bq, bk, bv, qb, kb, vb);
    transpose_v<<<dim3(32, 2, 64), 256, 0, stream>>>(vb, vtg);
    attn_kernel<<<1024, 128, 0, stream>>>(qb, kb, vtg, mask, Of);
    ln_kernel<<<2048, 256, 0, stream>>>(Of, g0, b0, O1b, O1f);
    gemm_mlp<<<dim3(4, 64, 1), 256, 0, stream>>>(O1b, wt, bo, O1f, Uf);
    ln_kernel<<<2048, 256, 0, stream>>>(Uf, g1, b1, nullptr, out);
}

// Round 3
// 232.739 us; speedup vs baseline: 1.0203x; 1.0203x over previous
//
#include <hip/hip_runtime.h>

// Interface (pinned): inputs fp32, mask int32, OUTPUT fp32.
// R12 = R10 structure (4 waves x 16q, grid 1024, 16 waves/CU, K staged in
// LDS via reg double-buffer, 2 barriers/tile) + R11's one good idea done
// right: V fragments NEVER touch LDS -- loaded direct global->VGPR, issued
// BEFORE the barrier and consumed only after QK+softmax (latency hidden
// under the compute phase, unlike R11 where they headed the chain).
//   R10 post-mortem: LDS pipe saturated (~370 LDS-cyc/wave/iter x 16
//   waves/CU x 16 iters ~ 95K of 110K cyc). Dropping V from LDS cuts this
//   to ~200 cyc/wave/iter (stage 2w + Kfrag 8r + P 16w_b16 + ap 2r).
//   R11 post-mortem: grid-capped 8 waves/CU + VMEM at head of chain =
//   latency-exposed, 77us. This round keeps 16 waves/CU and overlap.
// P path stays R8-verified RNE-bf16-through-LDS (per-wave, in-wave RAW,
// program-ordered, no barrier). Mask folded into exp2 bias (0/-30000).
// GEMMs/LNs/transposes and WS layout identical to R10/R11.

typedef float f32x4 __attribute__((ext_vector_type(4)));
typedef short bf16x8 __attribute__((ext_vector_type(8)));
typedef unsigned short u16;

#define MFMA16 __builtin_amdgcn_mfma_f32_16x16x32_bf16

__device__ __forceinline__ float bf2f(u16 u){
    unsigned x = ((unsigned)u) << 16;
    return __builtin_bit_cast(float, x);
}
__device__ __forceinline__ u16 f2bf(float f){  // round-to-nearest-even
    unsigned u = __builtin_bit_cast(unsigned, f);
    u = u + 0x7fffu + ((u >> 16) & 1u);
    return (u16)(u >> 16);
}

// ---------------------------------------------------------------------------
// Transpose + fp32->bf16 the 4 weight matrices (512x512).
// ---------------------------------------------------------------------------
__global__ __launch_bounds__(256) void transpose_w(
    const float* __restrict__ Wq, const float* __restrict__ Wk,
    const float* __restrict__ Wv, const float* __restrict__ Wo,
    u16* __restrict__ wt)
{
    const int z = blockIdx.z;
    const float* W = (z == 0) ? Wq : (z == 1) ? Wk : (z == 2) ? Wv : Wo;
    u16* out = wt + (size_t)z * 512 * 512;

    __shared__ u16 tile[32][33];
    const int k0 = blockIdx.y * 32, n0 = blockIdx.x * 32;
    const int c = threadIdx.x & 31, r = threadIdx.x >> 5;
#pragma unroll
    for (int i = 0; i < 4; i++) {
        int rr = r + i * 8;
        tile[rr][c] = f2bf(W[(size_t)(k0 + rr) * 512 + n0 + c]);
    }
    __syncthreads();
#pragma unroll
    for (int i = 0; i < 4; i++) {
        int rr = r + i * 8;
        out[(size_t)(n0 + rr) * 512 + k0 + c] = tile[c][rr];
    }
}

// ---------------------------------------------------------------------------
// Transpose V: vb[8192][512] (bf16) -> vtg[(b*8+h)*64 + d][1024 keys] (bf16).
// ---------------------------------------------------------------------------
__global__ __launch_bounds__(256) void transpose_v(
    const u16* __restrict__ vb, u16* __restrict__ vtg)
{
    __shared__ u16 tile[32][33];
    const int bh = blockIdx.z;              // 0..63
    const int b = bh >> 3, h = bh & 7;
    const int k0 = blockIdx.x * 32, d0 = blockIdx.y * 32;
    const int c = threadIdx.x & 31, r = threadIdx.x >> 5;
#pragma unroll
    for (int i = 0; i < 4; i++) {
        int rr = r + i * 8;
        tile[rr][c] = vb[(size_t)(b * 1024 + k0 + rr) * 512 + h * 64 + d0 + c];
    }
    __syncthreads();
#pragma unroll
    for (int i = 0; i < 4; i++) {
        int rr = r + i * 8;
        vtg[(size_t)(bh * 64 + d0 + rr) * 1024 + k0 + c] = tile[c][rr];
    }
}

// ---------------------------------------------------------------------------
// Projection GEMM (verified R5): C = X(fp32) @ W(bf16^T) + bias -> bf16.
// ---------------------------------------------------------------------------
__global__ __launch_bounds__(256) void gemm_proj(
    const float* __restrict__ Q, const float* __restrict__ K,
    const u16* __restrict__ wt,
    const float* __restrict__ bq, const float* __restrict__ bk, const float* __restrict__ bv,
    u16* __restrict__ qb, u16* __restrict__ kb, u16* __restrict__ vb)
{
    __shared__ __align__(16) u16 lds_a[128 * 40];
    __shared__ __align__(16) u16 lds_b[128 * 40];

    const int z = blockIdx.z;
    const float* X = (z == 0) ? Q : K;
    const u16* Wt = wt + (size_t)z * 512 * 512;
    const float* bias = (z == 0) ? bq : (z == 1) ? bk : bv;
    u16* outb = (z == 0) ? qb : (z == 1) ? kb : vb;

    const int bm = blockIdx.y, bn = blockIdx.x;
    const int t = threadIdx.x;
    const int wave = t >> 6, lane = t & 63, quad = lane >> 4, lm = lane & 15;
    const int wm = wave >> 1, wn = wave & 1;

    f32x4 acc[4][4];
    const f32x4 zz = {0.f, 0.f, 0.f, 0.f};
#pragma unroll
    for (int i = 0; i < 4; i++)
#pragma unroll
        for (int j = 0; j < 4; j++) acc[i][j] = zz;

    for (int k0 = 0; k0 < 512; k0 += 32) {
#pragma unroll
        for (int i = 0; i < 2; i++) {
            int idx = t + i * 256;
            int r = idx >> 2, c = (idx & 3) * 8;
            const float* xp = &X[(size_t)(bm * 128 + r) * 512 + k0 + c];
            f32x4 a0 = *(const f32x4*)xp;
            f32x4 a1 = *(const f32x4*)(xp + 4);
            bf16x8 xv;
#pragma unroll
            for (int j = 0; j < 4; j++) { xv[j] = (short)f2bf(a0[j]); xv[4 + j] = (short)f2bf(a1[j]); }
            *(bf16x8*)&lds_a[r * 40 + c] = xv;
            *(bf16x8*)&lds_b[r * 40 + c] =
                *(const bf16x8*)&Wt[(size_t)(bn * 128 + r) * 512 + k0 + c];
        }
        __syncthreads();
        bf16x8 af[4], bfr[4];
#pragma unroll
        for (int mi = 0; mi < 4; mi++)
            af[mi] = *(const bf16x8*)&lds_a[(wm * 64 + mi * 16 + lm) * 40 + quad * 8];
#pragma unroll
        for (int ni = 0; ni < 4; ni++)
            bfr[ni] = *(const bf16x8*)&lds_b[(wn * 64 + ni * 16 + lm) * 40 + quad * 8];
#pragma unroll
        for (int mi = 0; mi < 4; mi++)
#pragma unroll
            for (int ni = 0; ni < 4; ni++)
                acc[mi][ni] = MFMA16(af[mi], bfr[ni], acc[mi][ni], 0, 0, 0);
        __syncthreads();
    }

#pragma unroll
    for (int mi = 0; mi < 4; mi++) {
#pragma unroll
        for (int ni = 0; ni < 4; ni++) {
            const int col = bn * 128 + wn * 64 + ni * 16 + lm;
            const float bv_ = bias[col];
#pragma unroll
            for (int r = 0; r < 4; r++) {
                const int row = bm * 128 + wm * 64 + mi * 16 + quad * 4 + r;
                outb[(size_t)row * 512 + col] = f2bf(acc[mi][ni][r] + bv_);
            }
        }
    }
}

// ---------------------------------------------------------------------------
// MLP GEMM (verified R5): Uf = resid(fp32) + relu(X(bf16) @ Wo^T + bo) -> fp32.
// ---------------------------------------------------------------------------
__global__ __launch_bounds__(256) void gemm_mlp(
    const u16* __restrict__ X, const u16* __restrict__ wt,
    const float* __restrict__ bo, const float* __restrict__ resid,
    float* __restrict__ outf)
{
    __shared__ __align__(16) u16 lds_a[128 * 40];
    __shared__ __align__(16) u16 lds_b[128 * 40];

    const u16* Wt = wt + (size_t)3 * 512 * 512;
    const int bm = blockIdx.y, bn = blockIdx.x;
    const int t = threadIdx.x;
    const int wave = t >> 6, lane = t & 63, quad = lane >> 4, lm = lane & 15;
    const int wm = wave >> 1, wn = wave & 1;

    f32x4 acc[4][4];
    const f32x4 zz = {0.f, 0.f, 0.f, 0.f};
#pragma unroll
    for (int i = 0; i < 4; i++)
#pragma unroll
        for (int j = 0; j < 4; j++) acc[i][j] = zz;

    for (int k0 = 0; k0 < 512; k0 += 32) {
#pragma unroll
        for (int i = 0; i < 2; i++) {
            int idx = t + i * 256;
            int r = idx >> 2, c = (idx & 3) * 8;
            *(bf16x8*)&lds_a[r * 40 + c] =
                *(const bf16x8*)&X[(size_t)(bm * 128 + r) * 512 + k0 + c];
            *(bf16x8*)&lds_b[r * 40 + c] =
                *(const bf16x8*)&Wt[(size_t)(bn * 128 + r) * 512 + k0 + c];
        }
        __syncthreads();
        bf16x8 af[4], bfr[4];
#pragma unroll
        for (int mi = 0; mi < 4; mi++)
            af[mi] = *(const bf16x8*)&lds_a[(wm * 64 + mi * 16 + lm) * 40 + quad * 8];
#pragma unroll
        for (int ni = 0; ni < 4; ni++)
            bfr[ni] = *(const bf16x8*)&lds_b[(wn * 64 + ni * 16 + lm) * 40 + quad * 8];
#pragma unroll
        for (int mi = 0; mi < 4; mi++)
#pragma unroll
            for (int ni = 0; ni < 4; ni++)
                acc[mi][ni] = MFMA16(af[mi], bfr[ni], acc[mi][ni], 0, 0, 0);
        __syncthreads();
    }

#pragma unroll
    for (int mi = 0; mi < 4; mi++) {
#pragma unroll
        for (int ni = 0; ni < 4; ni++) {
            const int col = bn * 128 + wn * 64 + ni * 16 + lm;
            const float bv_ = bo[col];
#pragma unroll
            for (int r = 0; r < 4; r++) {
                const int row = bm * 128 + wm * 64 + mi * 16 + quad * 4 + r;
                const size_t off = (size_t)row * 512 + col;
                outf[off] = resid[off] + fmaxf(acc[mi][ni][r] + bv_, 0.f);
            }
        }
    }
}

// ---------------------------------------------------------------------------
// Attention v6: block = (b, h, 64 q-rows), 4 waves x 16 q. Grid 1024,
// 16 waves/CU. K staged in LDS (reg double-buffer, shared by 4 waves);
// V fragments direct global->VGPR, issued pre-barrier, consumed post-
// softmax (latency hidden under QK+softmax). 2 barriers/tile.
// P: R8-verified per-wave RNE-bf16-through-LDS. XCD-swizzled grid.
// ---------------------------------------------------------------------------
__global__ __launch_bounds__(256, 4) void attn_kernel(
    const u16* __restrict__ qb, const u16* __restrict__ kb, const u16* __restrict__ vtg,
    const int* __restrict__ mask, float* __restrict__ O)
{
    __shared__ __align__(16) u16 k_tile[64 * 88];       // [key][d]
    __shared__ __align__(16) u16 p_st[4 * 16 * 88];     // per-wave [qrow][key]
    __shared__ float mbias[1024];                       // 0 or -30000 (additive)

    // XCD swizzle: xcd = i&7; all 16 q-tiles of one (b,h) land on one XCD.
    const int i = blockIdx.x;
    const int s_ = i >> 3;
    const int bh = (i & 7) + 8 * (s_ >> 4);
    const int qt = s_ & 15;
    const int b = bh >> 3, h = bh & 7;

    const int t = threadIdx.x, wave = t >> 6, lane = t & 63;
    const int quad = lane >> 4, lm = lane & 15;
    const int qbase = qt * 64 + wave * 16;
    const size_t baseb = (size_t)b * 1024 * 512;
    const size_t vbase = (size_t)((b * 8 + h) * 64) * 1024;

#pragma unroll
    for (int ii = 0; ii < 4; ii++) {
        int j = t + ii * 256;
        mbias[j] = mask[b * 1024 + j] ? 0.0f : -30000.0f;
    }

    // Q A-frags: 1 m-tile (16 q-rows) x 2 d-halves
    bf16x8 aq[2];
#pragma unroll
    for (int ks = 0; ks < 2; ks++)
        aq[ks] = *(const bf16x8*)&qb[baseb +
            (size_t)(qbase + lm) * 512 + h * 64 + ks * 32 + quad * 8];

    float lsum[4] = {0.f, 0.f, 0.f, 0.f};
    f32x4 oacc[4];
    const f32x4 zz = {0.f, 0.f, 0.f, 0.f};
#pragma unroll
    for (int c = 0; c < 4; c++) oacc[c] = zz;

    const float SC2 = 0.125f * 1.44269504088896341f; // (1/sqrt(64)) * log2(e)
    const int srow = t >> 2, scol = (t & 3) * 16;    // K staging: 64 rows x 64
    u16* pw = &p_st[wave * 16 * 88];

    const u16* kgp = &kb[baseb + (size_t)srow * 512 + h * 64 + scol];

    bf16x8 kA0, kA1, kB0, kB1;

    auto load_k = [&](int kt, bf16x8& k0, bf16x8& k1) {
        const u16* kp = kgp + (size_t)kt * 64 * 512;
        k0 = *(const bf16x8*)kp;
        k1 = *(const bf16x8*)(kp + 8);
    };
    auto store_k = [&](bf16x8 k0, bf16x8 k1) {
        *(bf16x8*)&k_tile[srow * 88 + scol]     = k0;
        *(bf16x8*)&k_tile[srow * 88 + scol + 8] = k1;
    };
    // V fragments direct from global (B-frag of PV): [c][ks]. Same per-lane
    // addresses/values as the old LDS vt reads (bit-identical).
    auto load_v = [&](int kt, bf16x8 (&bvf)[4][2]) {
        const int keyg = kt * 64;
#pragma unroll
        for (int c = 0; c < 4; c++)
#pragma unroll
            for (int ks = 0; ks < 2; ks++)
                bvf[c][ks] = *(const bf16x8*)&vtg[vbase +
                    (size_t)(c * 16 + lm) * 1024 + keyg + ks * 32 + quad * 8];
    };

    auto compute_t = [&](int kt, const bf16x8 (&bvf)[4][2]) {
        const int keyg = kt * 64;
        bf16x8 bk[4][2];
#pragma unroll
        for (int n = 0; n < 4; n++)
#pragma unroll
            for (int ks = 0; ks < 2; ks++)
                bk[n][ks] = *(const bf16x8*)&k_tile[(n * 16 + lm) * 88 + ks * 32 + quad * 8];

#pragma unroll
        for (int n = 0; n < 4; n++) {
            f32x4 S = zz;
            __builtin_amdgcn_s_setprio(1);
            S = MFMA16(aq[0], bk[n][0], S, 0, 0, 0);
            S = MFMA16(aq[1], bk[n][1], S, 0, 0, 0);
            __builtin_amdgcn_s_setprio(0);
            const float bias = mbias[keyg + n * 16 + lm];
#pragma unroll
            for (int r = 0; r < 4; r++) {
                float p = __builtin_amdgcn_exp2f(__builtin_fmaf(S[r], SC2, bias));
                lsum[r] += p;
                pw[(quad * 4 + r) * 88 + n * 16 + lm] = f2bf(p);
            }
        }
        // no barrier: pw is per-wave; in-wave LDS RAW is program-ordered.

#pragma unroll
        for (int ks = 0; ks < 2; ks++) {
            bf16x8 ap = *(const bf16x8*)&pw[lm * 88 + ks * 32 + quad * 8];
            __builtin_amdgcn_s_setprio(1);
#pragma unroll
            for (int c = 0; c < 4; c++)
                oacc[c] = MFMA16(ap, bvf[c][ks], oacc[c], 0, 0, 0);
            __builtin_amdgcn_s_setprio(0);
        }
    };

    // prologue: tile 0's K into regs
    load_k(0, kA0, kA1);

    bf16x8 bvf[4][2];

    for (int kt = 0; kt < 16; kt += 2) {
        store_k(kA0, kA1);                    // vmcnt drain for K(kt)
        load_k(kt + 1, kB0, kB1);             // issue K(kt+1)
        load_v(kt, bvf);                      // issue V(kt): consumed post-softmax
        __syncthreads();
        compute_t(kt, bvf);
        __syncthreads();
        store_k(kB0, kB1);
        load_k((kt + 2) & 15, kA0, kA1);      // &15: last iter dead-loads tile 0
        load_v(kt + 1, bvf);
        __syncthreads();
        compute_t(kt + 1, bvf);
        __syncthreads();
    }

    // reduce lsum across the 16 key-columns (lanes lm within each quad)
#pragma unroll
    for (int r = 0; r < 4; r++) {
        float s = lsum[r];
        s += __shfl_xor(s, 1); s += __shfl_xor(s, 2);
        s += __shfl_xor(s, 4); s += __shfl_xor(s, 8);
        lsum[r] = s;
    }

    // epilogue: O = q + P.V / l  (fp32, coalesced over lm)
#pragma unroll
    for (int c = 0; c < 4; c++)
#pragma unroll
        for (int r = 0; r < 4; r++) {
            const int row = qbase + quad * 4 + r;
            const int d = h * 64 + c * 16 + lm;
            const size_t off = baseb + (size_t)row * 512 + d;
            O[off] = bf2f(qb[off]) + oacc[c][r] / lsum[r];
        }
}

// ---------------------------------------------------------------------------
// Row LayerNorm over 512 (verified R5): fp32 in; optional bf16 + fp32 outs.
// ---------------------------------------------------------------------------
__global__ __launch_bounds__(256) void ln_kernel(
    const float* __restrict__ in, const float* __restrict__ g, const float* __restrict__ bsh,
    u16* __restrict__ outb, float* __restrict__ outf)
{
    const int row = blockIdx.x * 4 + (threadIdx.x >> 6);
    const int lane = threadIdx.x & 63;
    const float* x = in + (size_t)row * 512 + lane * 8;
    float v[8];
    *(f32x4*)&v[0] = *(const f32x4*)&x[0];
    *(f32x4*)&v[4] = *(const f32x4*)&x[4];
    float s = 0.f, sq = 0.f;
#pragma unroll
    for (int j = 0; j < 8; j++) { s += v[j]; sq += v[j] * v[j]; }
#pragma unroll
    for (int off = 1; off < 64; off <<= 1) {
        s += __shfl_xor(s, off);
        sq += __shfl_xor(sq, off);
    }
    const float mu = s * (1.f / 512.f);
    const float var = sq * (1.f / 512.f) - mu * mu;
    const float rs = rsqrtf(var + 1e-5f);
    float y[8];
#pragma unroll
    for (int j = 0; j < 8; j++) {
        int col = lane * 8 + j;
        y[j] = (v[j] - mu) * rs * g[col] + bsh[col];
    }
    if (outb != nullptr) {
        bf16x8 ov;
#pragma unroll
        for (int j = 0; j < 8; j++) ov[j] = (short)f2bf(y[j]);
        *(bf16x8*)&outb[(size_t)row * 512 + lane * 8] = ov;
    }
    if (outf != nullptr) {
        float* o = outf + (size_t)row * 512 + lane * 8;
        *(f32x4*)&o[0] = *(const f32x4*)&y[0];
        *(f32x4*)&o[4] = *(const f32x4*)&y[4];
    }
}

extern "C" void kernel_launch(void* const* d_in, const int* in_sizes, int n_in,
                              void* d_out, int out_size, void* d_ws, size_t ws_size,
                              hipStream_t stream) {
    const float* Q  = (const float*)d_in[0];
    const float* K  = (const float*)d_in[1];
    const int* mask = (const int*)d_in[2];
    const float* Wq = (const float*)d_in[3];
    const float* bq = (const float*)d_in[4];
    const float* Wk = (const float*)d_in[5];
    const float* bk = (const float*)d_in[6];
    const float* Wv = (const float*)d_in[7];
    const float* bv = (const float*)d_in[8];
    const float* Wo = (const float*)d_in[9];
    const float* bo = (const float*)d_in[10];
    const float* g0 = (const float*)d_in[11];
    const float* b0 = (const float*)d_in[12];
    const float* g1 = (const float*)d_in[13];
    const float* b1 = (const float*)d_in[14];
    float* out = (float*)d_out;

    char* ws = (char*)d_ws;
    const size_t MB = 1048576;
    u16*   wt  = (u16*)(ws);
    u16*   qb  = (u16*)(ws + 2 * MB);
    u16*   kb  = (u16*)(ws + 10 * MB);
    u16*   vtg = (u16*)(ws + 18 * MB);
    u16*   vb  = (u16*)(ws + 26 * MB);
    float* Of  = (float*)(ws + 26 * MB);  // overwrites vb (dead after transpose_v)
    u16*   O1b = (u16*)(ws + 2 * MB);     // reuse qb
    float* O1f = (float*)(ws + 10 * MB);  // reuse kb+vtg
    float* Uf  = (float*)(ws + 26 * MB);  // reuse Of

    transpose_w<<<dim3(16, 16, 4), 256, 0, stream>>>(Wq, Wk, Wv, Wo, wt);
    gemm_proj<<<dim3(4, 64, 3), 256, 0, stream>>>(Q, K, wt, bq, bk, bv, qb, kb, vb);
    transpose_v<<<dim3(32, 2, 64), 256, 0, stream>>>(vb, vtg);
    attn_kernel<<<1024, 256, 0, stream>>>(qb, kb, vtg, mask, Of);
    ln_kernel<<<2048, 256, 0, stream>>>(Of, g0, b0, O1b, O1f);
    gemm_mlp<<<dim3(4, 64, 1), 256, 0, stream>>>(O1b, wt, bo, O1f, Uf);
    ln_kernel<<<2048, 256, 0, stream>>>(Uf, g1, b1, nullptr, out);
}

// Round 4
// 214.001 us; speedup vs baseline: 1.1097x; 1.0876x over previous
//
#include <hip/hip_runtime.h>

// Interface (pinned): inputs fp32, mask int32, OUTPUT fp32.
// R13: attn reverted to the verified R10 structure (best measured, 46us);
// R11/R12 post-mortem: direct-global V/K fragment loads are 16-segment
// gathers -- scattered VMEM cost >> LDS savings. Only coalesced-VMEM-
// preserving LDS cuts are allowed:
//   - attn: mask bias from 4 coalesced VMEM loads/tile instead of LDS
//     (removes mbias staging + 8 LDS reads/wave-tile; -13% LDS traffic).
// Pipeline-side (161us of 207 is OUTSIDE attn):
//   - convert_x: Q,K fp32 -> bf16 ONCE (bit-identical RNE f2bf). gemm_proj
//     A-stage becomes one bf16x8 load: halves A traffic (4x bn-redundant)
//     and deletes per-iter f2bf VALU from the inner loop.
//   - gemm_proj z==2 writes V directly TRANSPOSED to vtg (packed u16x4,
//     4 contiguous keys): transpose_v kernel deleted.
// All value paths bit-identical to R10 (absmax expected 0.03125).
// WS peak unchanged 42 MiB: xq/xk live in the dead-until-attn Of region.

typedef float f32x4 __attribute__((ext_vector_type(4)));
typedef short bf16x8 __attribute__((ext_vector_type(8)));
typedef unsigned short u16;
typedef unsigned short u16x4 __attribute__((ext_vector_type(4)));

#define MFMA16 __builtin_amdgcn_mfma_f32_16x16x32_bf16

__device__ __forceinline__ float bf2f(u16 u){
    unsigned x = ((unsigned)u) << 16;
    return __builtin_bit_cast(float, x);
}
__device__ __forceinline__ u16 f2bf(float f){  // round-to-nearest-even
    unsigned u = __builtin_bit_cast(unsigned, f);
    u = u + 0x7fffu + ((u >> 16) & 1u);
    return (u16)(u >> 16);
}

// ---------------------------------------------------------------------------
// Transpose + fp32->bf16 the 4 weight matrices (512x512).
// ---------------------------------------------------------------------------
__global__ __launch_bounds__(256) void transpose_w(
    const float* __restrict__ Wq, const float* __restrict__ Wk,
    const float* __restrict__ Wv, const float* __restrict__ Wo,
    u16* __restrict__ wt)
{
    const int z = blockIdx.z;
    const float* W = (z == 0) ? Wq : (z == 1) ? Wk : (z == 2) ? Wv : Wo;
    u16* out = wt + (size_t)z * 512 * 512;

    __shared__ u16 tile[32][33];
    const int k0 = blockIdx.y * 32, n0 = blockIdx.x * 32;
    const int c = threadIdx.x & 31, r = threadIdx.x >> 5;
#pragma unroll
    for (int i = 0; i < 4; i++) {
        int rr = r + i * 8;
        tile[rr][c] = f2bf(W[(size_t)(k0 + rr) * 512 + n0 + c]);
    }
    __syncthreads();
#pragma unroll
    for (int i = 0; i < 4; i++) {
        int rr = r + i * 8;
        out[(size_t)(n0 + rr) * 512 + k0 + c] = tile[c][rr];
    }
}

// ---------------------------------------------------------------------------
// Convert Q,K fp32 -> bf16 once (RNE, bit-identical to the old in-GEMM f2bf).
// 8 elements/thread, fully coalesced.
// ---------------------------------------------------------------------------
__global__ __launch_bounds__(256) void convert_x(
    const float* __restrict__ Q, const float* __restrict__ K,
    u16* __restrict__ xq, u16* __restrict__ xk)
{
    const float* src = blockIdx.y ? K : Q;
    u16* dst = blockIdx.y ? xk : xq;
    const size_t i = ((size_t)blockIdx.x * 256 + threadIdx.x) * 8;
    f32x4 a0 = *(const f32x4*)&src[i];
    f32x4 a1 = *(const f32x4*)&src[i + 4];
    bf16x8 v;
#pragma unroll
    for (int j = 0; j < 4; j++) { v[j] = (short)f2bf(a0[j]); v[4 + j] = (short)f2bf(a1[j]); }
    *(bf16x8*)&dst[i] = v;
}

// ---------------------------------------------------------------------------
// Projection GEMM: C = X(bf16) @ W(bf16^T) + bias.
// z==0 -> qb, z==1 -> kb, z==2 -> writes vtg DIRECTLY transposed
// ([(b*8+h)*64+d][key], packed 4 keys per store). Values bit-identical.
// ---------------------------------------------------------------------------
__global__ __launch_bounds__(256) void gemm_proj(
    const u16* __restrict__ xq, const u16* __restrict__ xk,
    const u16* __restrict__ wt,
    const float* __restrict__ bq, const float* __restrict__ bk, const float* __restrict__ bv,
    u16* __restrict__ qb, u16* __restrict__ kb, u16* __restrict__ vtg)
{
    __shared__ __align__(16) u16 lds_a[128 * 40];
    __shared__ __align__(16) u16 lds_b[128 * 40];

    const int z = blockIdx.z;
    const u16* X = (z == 0) ? xq : xk;
    const u16* Wt = wt + (size_t)z * 512 * 512;
    const float* bias = (z == 0) ? bq : (z == 1) ? bk : bv;
    u16* outb = (z == 0) ? qb : kb;

    const int bm = blockIdx.y, bn = blockIdx.x;
    const int t = threadIdx.x;
    const int wave = t >> 6, lane = t & 63, quad = lane >> 4, lm = lane & 15;
    const int wm = wave >> 1, wn = wave & 1;

    f32x4 acc[4][4];
    const f32x4 zz = {0.f, 0.f, 0.f, 0.f};
#pragma unroll
    for (int i = 0; i < 4; i++)
#pragma unroll
        for (int j = 0; j < 4; j++) acc[i][j] = zz;

    for (int k0 = 0; k0 < 512; k0 += 32) {
#pragma unroll
        for (int i = 0; i < 2; i++) {
            int idx = t + i * 256;
            int r = idx >> 2, c = (idx & 3) * 8;
            *(bf16x8*)&lds_a[r * 40 + c] =
                *(const bf16x8*)&X[(size_t)(bm * 128 + r) * 512 + k0 + c];
            *(bf16x8*)&lds_b[r * 40 + c] =
                *(const bf16x8*)&Wt[(size_t)(bn * 128 + r) * 512 + k0 + c];
        }
        __syncthreads();
        bf16x8 af[4], bfr[4];
#pragma unroll
        for (int mi = 0; mi < 4; mi++)
            af[mi] = *(const bf16x8*)&lds_a[(wm * 64 + mi * 16 + lm) * 40 + quad * 8];
#pragma unroll
        for (int ni = 0; ni < 4; ni++)
            bfr[ni] = *(const bf16x8*)&lds_b[(wn * 64 + ni * 16 + lm) * 40 + quad * 8];
#pragma unroll
        for (int mi = 0; mi < 4; mi++)
#pragma unroll
            for (int ni = 0; ni < 4; ni++)
                acc[mi][ni] = MFMA16(af[mi], bfr[ni], acc[mi][ni], 0, 0, 0);
        __syncthreads();
    }

    if (z == 2) {
        // direct transposed V write: vtg[((b*8+h)*64 + d)*1024 + key]
#pragma unroll
        for (int mi = 0; mi < 4; mi++) {
            const int key0 = bm * 128 + wm * 64 + mi * 16 + quad * 4;
            const int bb = key0 >> 10, key = key0 & 1023;
#pragma unroll
            for (int ni = 0; ni < 4; ni++) {
                const int col = bn * 128 + wn * 64 + ni * 16 + lm;
                const float bv_ = bias[col];
                const int hh = col >> 6, dd = col & 63;
                u16x4 pk;
#pragma unroll
                for (int r = 0; r < 4; r++) pk[r] = f2bf(acc[mi][ni][r] + bv_);
                *(u16x4*)&vtg[((size_t)((bb * 8 + hh) * 64 + dd)) * 1024 + key] = pk;
            }
        }
    } else {
#pragma unroll
        for (int mi = 0; mi < 4; mi++) {
#pragma unroll
            for (int ni = 0; ni < 4; ni++) {
                const int col = bn * 128 + wn * 64 + ni * 16 + lm;
                const float bv_ = bias[col];
#pragma unroll
                for (int r = 0; r < 4; r++) {
                    const int row = bm * 128 + wm * 64 + mi * 16 + quad * 4 + r;
                    outb[(size_t)row * 512 + col] = f2bf(acc[mi][ni][r] + bv_);
                }
            }
        }
    }
}

// ---------------------------------------------------------------------------
// MLP GEMM (verified R5): Uf = resid(fp32) + relu(X(bf16) @ Wo^T + bo) -> fp32.
// ---------------------------------------------------------------------------
__global__ __launch_bounds__(256) void gemm_mlp(
    const u16* __restrict__ X, const u16* __restrict__ wt,
    const float* __restrict__ bo, const float* __restrict__ resid,
    float* __restrict__ outf)
{
    __shared__ __align__(16) u16 lds_a[128 * 40];
    __shared__ __align__(16) u16 lds_b[128 * 40];

    const u16* Wt = wt + (size_t)3 * 512 * 512;
    const int bm = blockIdx.y, bn = blockIdx.x;
    const int t = threadIdx.x;
    const int wave = t >> 6, lane = t & 63, quad = lane >> 4, lm = lane & 15;
    const int wm = wave >> 1, wn = wave & 1;

    f32x4 acc[4][4];
    const f32x4 zz = {0.f, 0.f, 0.f, 0.f};
#pragma unroll
    for (int i = 0; i < 4; i++)
#pragma unroll
        for (int j = 0; j < 4; j++) acc[i][j] = zz;

    for (int k0 = 0; k0 < 512; k0 += 32) {
#pragma unroll
        for (int i = 0; i < 2; i++) {
            int idx = t + i * 256;
            int r = idx >> 2, c = (idx & 3) * 8;
            *(bf16x8*)&lds_a[r * 40 + c] =
                *(const bf16x8*)&X[(size_t)(bm * 128 + r) * 512 + k0 + c];
            *(bf16x8*)&lds_b[r * 40 + c] =
                *(const bf16x8*)&Wt[(size_t)(bn * 128 + r) * 512 + k0 + c];
        }
        __syncthreads();
        bf16x8 af[4], bfr[4];
#pragma unroll
        for (int mi = 0; mi < 4; mi++)
            af[mi] = *(const bf16x8*)&lds_a[(wm * 64 + mi * 16 + lm) * 40 + quad * 8];
#pragma unroll
        for (int ni = 0; ni < 4; ni++)
            bfr[ni] = *(const bf16x8*)&lds_b[(wn * 64 + ni * 16 + lm) * 40 + quad * 8];
#pragma unroll
        for (int mi = 0; mi < 4; mi++)
#pragma unroll
            for (int ni = 0; ni < 4; ni++)
                acc[mi][ni] = MFMA16(af[mi], bfr[ni], acc[mi][ni], 0, 0, 0);
        __syncthreads();
    }

#pragma unroll
    for (int mi = 0; mi < 4; mi++) {
#pragma unroll
        for (int ni = 0; ni < 4; ni++) {
            const int col = bn * 128 + wn * 64 + ni * 16 + lm;
            const float bv_ = bo[col];
#pragma unroll
            for (int r = 0; r < 4; r++) {
                const int row = bm * 128 + wm * 64 + mi * 16 + quad * 4 + r;
                const size_t off = (size_t)row * 512 + col;
                outf[off] = resid[off] + fmaxf(acc[mi][ni][r] + bv_, 0.f);
            }
        }
    }
}

// ---------------------------------------------------------------------------
// Attention (R10-verified structure): block = (b, h, 64 q-rows), 4 waves x
// 16 q, grid 1024, 16 waves/CU. K AND V staged in LDS via reg double-buffer
// (coalesced VMEM); 2 barriers/tile. Only change vs R10: mask bias comes
// from 4 coalesced VMEM loads/tile (mbias LDS array + staging removed).
// P: R8-verified per-wave RNE-bf16-through-LDS. XCD-swizzled grid.
// ---------------------------------------------------------------------------
__global__ __launch_bounds__(256, 4) void attn_kernel(
    const u16* __restrict__ qb, const u16* __restrict__ kb, const u16* __restrict__ vtg,
    const int* __restrict__ mask, float* __restrict__ O)
{
    __shared__ __align__(16) u16 k_tile[64 * 88];       // [key][d]
    __shared__ __align__(16) u16 vt[64 * 88];           // [d][key]
    __shared__ __align__(16) u16 p_st[4 * 16 * 88];     // per-wave [qrow][key]

    // XCD swizzle: xcd = i&7; all 16 q-tiles of one (b,h) land on one XCD.
    const int i = blockIdx.x;
    const int s_ = i >> 3;
    const int bh = (i & 7) + 8 * (s_ >> 4);
    const int qt = s_ & 15;
    const int b = bh >> 3, h = bh & 7;

    const int t = threadIdx.x, wave = t >> 6, lane = t & 63;
    const int quad = lane >> 4, lm = lane & 15;
    const int qbase = qt * 64 + wave * 16;
    const size_t baseb = (size_t)b * 1024 * 512;
    const size_t vbase = (size_t)((b * 8 + h) * 64) * 1024;
    const int* mrow = &mask[b * 1024];

    // Q A-frags: 1 m-tile (16 q-rows) x 2 d-halves
    bf16x8 aq[2];
#pragma unroll
    for (int ks = 0; ks < 2; ks++)
        aq[ks] = *(const bf16x8*)&qb[baseb +
            (size_t)(qbase + lm) * 512 + h * 64 + ks * 32 + quad * 8];

    float lsum[4] = {0.f, 0.f, 0.f, 0.f};
    f32x4 oacc[4];
    const f32x4 zz = {0.f, 0.f, 0.f, 0.f};
#pragma unroll
    for (int c = 0; c < 4; c++) oacc[c] = zz;

    const float SC2 = 0.125f * 1.44269504088896341f; // (1/sqrt(64)) * log2(e)
    const int srow = t >> 2, scol = (t & 3) * 16;    // staging: 64 rows x 64
    u16* pw = &p_st[wave * 16 * 88];

    const u16* kgp = &kb[baseb + (size_t)srow * 512 + h * 64 + scol];
    const u16* vgp = &vtg[vbase + (size_t)srow * 1024 + scol];

    bf16x8 kA0, kA1, vA0, vA1, kB0, kB1, vB0, vB1;

    auto load_t = [&](int kt, bf16x8& k0, bf16x8& k1, bf16x8& v0, bf16x8& v1) {
        const u16* kp = kgp + (size_t)kt * 64 * 512;
        k0 = *(const bf16x8*)kp;
        k1 = *(const bf16x8*)(kp + 8);
        const u16* vp = vgp + kt * 64;
        v0 = *(const bf16x8*)vp;
        v1 = *(const bf16x8*)(vp + 8);
    };
    auto store_t = [&](bf16x8 k0, bf16x8 k1, bf16x8 v0, bf16x8 v1) {
        *(bf16x8*)&k_tile[srow * 88 + scol]     = k0;
        *(bf16x8*)&k_tile[srow * 88 + scol + 8] = k1;
        *(bf16x8*)&vt[srow * 88 + scol]     = v0;
        *(bf16x8*)&vt[srow * 88 + scol + 8] = v1;
    };

    auto compute_t = [&](int kt) {
        const int keyg = kt * 64;
        // mask bias per n-tile via coalesced VMEM (0 / -30000, same values)
        float bias_n[4];
#pragma unroll
        for (int n = 0; n < 4; n++)
            bias_n[n] = mrow[keyg + n * 16 + lm] ? 0.0f : -30000.0f;

        bf16x8 bk[4][2];
#pragma unroll
        for (int n = 0; n < 4; n++)
#pragma unroll
            for (int ks = 0; ks < 2; ks++)
                bk[n][ks] = *(const bf16x8*)&k_tile[(n * 16 + lm) * 88 + ks * 32 + quad * 8];

#pragma unroll
        for (int n = 0; n < 4; n++) {
            f32x4 S = zz;
            __builtin_amdgcn_s_setprio(1);
            S = MFMA16(aq[0], bk[n][0], S, 0, 0, 0);
            S = MFMA16(aq[1], bk[n][1], S, 0, 0, 0);
            __builtin_amdgcn_s_setprio(0);
#pragma unroll
            for (int r = 0; r < 4; r++) {
                float p = __builtin_amdgcn_exp2f(__builtin_fmaf(S[r], SC2, bias_n[n]));
                lsum[r] += p;
                pw[(quad * 4 + r) * 88 + n * 16 + lm] = f2bf(p);
            }
        }
        // no barrier: pw is per-wave; in-wave LDS RAW is program-ordered.

#pragma unroll
        for (int ks = 0; ks < 2; ks++) {
            bf16x8 ap = *(const bf16x8*)&pw[lm * 88 + ks * 32 + quad * 8];
            __builtin_amdgcn_s_setprio(1);
#pragma unroll
            for (int c = 0; c < 4; c++) {
                bf16x8 bv_ = *(const bf16x8*)&vt[(c * 16 + lm) * 88 + ks * 32 + quad * 8];
                oacc[c] = MFMA16(ap, bv_, oacc[c], 0, 0, 0);
            }
            __builtin_amdgcn_s_setprio(0);
        }
    };

    // prologue: tile 0 into regs
    load_t(0, kA0, kA1, vA0, vA1);

    for (int kt = 0; kt < 16; kt += 2) {
        store_t(kA0, kA1, vA0, vA1);          // vmcnt wait for tile kt here
        load_t(kt + 1, kB0, kB1, vB0, vB1);   // issue tile kt+1 (hidden)
        __syncthreads();
        compute_t(kt);
        __syncthreads();
        store_t(kB0, kB1, vB0, vB1);
        load_t((kt + 2) & 15, kA0, kA1, vA0, vA1); // &15: last iter dead-loads tile 0
        __syncthreads();
        compute_t(kt + 1);
        __syncthreads();
    }

    // reduce lsum across the 16 key-columns (lanes lm within each quad)
#pragma unroll
    for (int r = 0; r < 4; r++) {
        float s = lsum[r];
        s += __shfl_xor(s, 1); s += __shfl_xor(s, 2);
        s += __shfl_xor(s, 4); s += __shfl_xor(s, 8);
        lsum[r] = s;
    }

    // epilogue: O = q + P.V / l  (fp32, coalesced over lm)
#pragma unroll
    for (int c = 0; c < 4; c++)
#pragma unroll
        for (int r = 0; r < 4; r++) {
            const int row = qbase + quad * 4 + r;
            const int d = h * 64 + c * 16 + lm;
            const size_t off = baseb + (size_t)row * 512 + d;
            O[off] = bf2f(qb[off]) + oacc[c][r] / lsum[r];
        }
}

// ---------------------------------------------------------------------------
// Row LayerNorm over 512 (verified R5): fp32 in; optional bf16 + fp32 outs.
// ---------------------------------------------------------------------------
__global__ __launch_bounds__(256) void ln_kernel(
    const float* __restrict__ in, const float* __restrict__ g, const float* __restrict__ bsh,
    u16* __restrict__ outb, float* __restrict__ outf)
{
    const int row = blockIdx.x * 4 + (threadIdx.x >> 6);
    const int lane = threadIdx.x & 63;
    const float* x = in + (size_t)row * 512 + lane * 8;
    float v[8];
    *(f32x4*)&v[0] = *(const f32x4*)&x[0];
    *(f32x4*)&v[4] = *(const f32x4*)&x[4];
    float s = 0.f, sq = 0.f;
#pragma unroll
    for (int j = 0; j < 8; j++) { s += v[j]; sq += v[j] * v[j]; }
#pragma unroll
    for (int off = 1; off < 64; off <<= 1) {
        s += __shfl_xor(s, off);
        sq += __shfl_xor(sq, off);
    }
    const float mu = s * (1.f / 512.f);
    const float var = sq * (1.f / 512.f) - mu * mu;
    const float rs = rsqrtf(var + 1e-5f);
    float y[8];
#pragma unroll
    for (int j = 0; j < 8; j++) {
        int col = lane * 8 + j;
        y[j] = (v[j] - mu) * rs * g[col] + bsh[col];
    }
    if (outb != nullptr) {
        bf16x8 ov;
#pragma unroll
        for (int j = 0; j < 8; j++) ov[j] = (short)f2bf(y[j]);
        *(bf16x8*)&outb[(size_t)row * 512 + lane * 8] = ov;
    }
    if (outf != nullptr) {
        float* o = outf + (size_t)row * 512 + lane * 8;
        *(f32x4*)&o[0] = *(const f32x4*)&y[0];
        *(f32x4*)&o[4] = *(const f32x4*)&y[4];
    }
}

extern "C" void kernel_launch(void* const* d_in, const int* in_sizes, int n_in,
                              void* d_out, int out_size, void* d_ws, size_t ws_size,
                              hipStream_t stream) {
    const float* Q  = (const float*)d_in[0];
    const float* K  = (const float*)d_in[1];
    const int* mask = (const int*)d_in[2];
    const float* Wq = (const float*)d_in[3];
    const float* bq = (const float*)d_in[4];
    const float* Wk = (const float*)d_in[5];
    const float* bk = (const float*)d_in[6];
    const float* Wv = (const float*)d_in[7];
    const float* bv = (const float*)d_in[8];
    const float* Wo = (const float*)d_in[9];
    const float* bo = (const float*)d_in[10];
    const float* g0 = (const float*)d_in[11];
    const float* b0 = (const float*)d_in[12];
    const float* g1 = (const float*)d_in[13];
    const float* b1 = (const float*)d_in[14];
    float* out = (float*)d_out;

    char* ws = (char*)d_ws;
    const size_t MB = 1048576;
    u16*   wt  = (u16*)(ws);              // 0-2 MB, live to gemm_mlp
    u16*   qb  = (u16*)(ws + 2 * MB);     // 2-10, live to attn
    u16*   kb  = (u16*)(ws + 10 * MB);    // 10-18, live to attn
    u16*   vtg = (u16*)(ws + 18 * MB);    // 18-26, live to attn
    u16*   xq  = (u16*)(ws + 26 * MB);    // 26-34, dead after gemm_proj
    u16*   xk  = (u16*)(ws + 34 * MB);    // 34-42, dead after gemm_proj
    float* Of  = (float*)(ws + 26 * MB);  // 26-42, written by attn (after proj)
    u16*   O1b = (u16*)(ws + 2 * MB);     // reuse qb (dead after attn)
    float* O1f = (float*)(ws + 10 * MB);  // reuse kb+vtg (dead after attn)
    float* Uf  = (float*)(ws + 26 * MB);  // reuse Of

    transpose_w<<<dim3(16, 16, 4), 256, 0, stream>>>(Wq, Wk, Wv, Wo, wt);
    convert_x<<<dim3(2048, 2), 256, 0, stream>>>(Q, K, xq, xk);
    gemm_proj<<<dim3(4, 64, 3), 256, 0, stream>>>(xq, xk, wt, bq, bk, bv, qb, kb, vtg);
    attn_kernel<<<1024, 256, 0, stream>>>(qb, kb, vtg, mask, Of);
    ln_kernel<<<2048, 256, 0, stream>>>(Of, g0, b0, O1b, O1f);
    gemm_mlp<<<dim3(4, 64, 1), 256, 0, stream>>>(O1b, wt, bo, O1f, Uf);
    ln_kernel<<<2048, 256, 0, stream>>>(Uf, g1, b1, nullptr, out);
}

// Round 5
// 206.027 us; speedup vs baseline: 1.1526x; 1.0387x over previous
//
#include <hip/hip_runtime.h>

// Interface (pinned): inputs fp32, mask int32, OUTPUT fp32.
// R14 = R9 pipeline (fp32-A gemm_proj + vb + transpose_v: the verified
// non-attn side; R13's scattered z==2 vtg write and convert_x reverted to
// isolate variables) + attn rebuilt with REGISTER-RESIDENT P (T12/16x16):
//   - QK computed SWAPPED: S^T = mfma(K,Q). Same products, same MFMA
//     k-tree => bit-identical S values, transposed placement. K-frag LDS
//     reads unchanged (A/B frags share the same lane layout).
//   - P packed in registers with the R8-verified RNE f2bf (bit-identical
//     bits to the old LDS path), then redistributed to the PV A-frag
//     layout with 4x v_permlane32_swap + 4x v_permlane16_swap per tile
//     (VALU pipe) -- the LDS P round-trip (16 ds_write_b16 + 2
//     ds_read_b128 per wave-tile, ~33% of LDS traffic) is DELETED.
//   - mask bias via one int4 VMEM load per n-tile (key axis = r index).
//   - LDS/block 22.5KB (k_tile + vt only), 4 blocks/CU, 16 waves/CU.
// PV accumulation order and P bits identical to R13; only lsum's fp32
// add order changes (<< tolerance).

typedef float f32x4 __attribute__((ext_vector_type(4)));
typedef short bf16x8 __attribute__((ext_vector_type(8)));
typedef unsigned short u16;
typedef unsigned int u32;
typedef unsigned int u32x2 __attribute__((ext_vector_type(2)));
typedef unsigned int u32x4 __attribute__((ext_vector_type(4)));
typedef int i32x4 __attribute__((ext_vector_type(4)));

#define MFMA16 __builtin_amdgcn_mfma_f32_16x16x32_bf16

__device__ __forceinline__ float bf2f(u16 u){
    unsigned x = ((unsigned)u) << 16;
    return __builtin_bit_cast(float, x);
}
__device__ __forceinline__ u16 f2bf(float f){  // round-to-nearest-even
    unsigned u = __builtin_bit_cast(unsigned, f);
    u = u + 0x7fffu + ((u >> 16) & 1u);
    return (u16)(u >> 16);
}

// permlane swaps (gfx950). Semantics:
//   p32: a' = [a.lo32 | b.lo32], b' = [a.hi32 | b.hi32]
//   p16: a' = [a.r0 | b.r0 | a.r2 | b.r2], b' = [a.r1 | b.r1 | a.r3 | b.r3]
__device__ __forceinline__ void plane32_swap(u32& a, u32& b){
#if __has_builtin(__builtin_amdgcn_permlane32_swap)
    u32x2 r = __builtin_amdgcn_permlane32_swap(a, b, false, false);
    a = r[0]; b = r[1];
#else
    asm volatile("v_permlane32_swap_b32 %0, %1" : "+v"(a), "+v"(b));
#endif
}
__device__ __forceinline__ void plane16_swap(u32& a, u32& b){
#if __has_builtin(__builtin_amdgcn_permlane16_swap)
    u32x2 r = __builtin_amdgcn_permlane16_swap(a, b, false, false);
    a = r[0]; b = r[1];
#else
    asm volatile("v_permlane16_swap_b32 %0, %1" : "+v"(a), "+v"(b));
#endif
}

// ---------------------------------------------------------------------------
// Transpose + fp32->bf16 the 4 weight matrices (512x512).
// ---------------------------------------------------------------------------
__global__ __launch_bounds__(256) void transpose_w(
    const float* __restrict__ Wq, const float* __restrict__ Wk,
    const float* __restrict__ Wv, const float* __restrict__ Wo,
    u16* __restrict__ wt)
{
    const int z = blockIdx.z;
    const float* W = (z == 0) ? Wq : (z == 1) ? Wk : (z == 2) ? Wv : Wo;
    u16* out = wt + (size_t)z * 512 * 512;

    __shared__ u16 tile[32][33];
    const int k0 = blockIdx.y * 32, n0 = blockIdx.x * 32;
    const int c = threadIdx.x & 31, r = threadIdx.x >> 5;
#pragma unroll
    for (int i = 0; i < 4; i++) {
        int rr = r + i * 8;
        tile[rr][c] = f2bf(W[(size_t)(k0 + rr) * 512 + n0 + c]);
    }
    __syncthreads();
#pragma unroll
    for (int i = 0; i < 4; i++) {
        int rr = r + i * 8;
        out[(size_t)(n0 + rr) * 512 + k0 + c] = tile[c][rr];
    }
}

// ---------------------------------------------------------------------------
// Transpose V: vb[8192][512] (bf16) -> vtg[(b*8+h)*64 + d][1024 keys] (bf16).
// ---------------------------------------------------------------------------
__global__ __launch_bounds__(256) void transpose_v(
    const u16* __restrict__ vb, u16* __restrict__ vtg)
{
    __shared__ u16 tile[32][33];
    const int bh = blockIdx.z;              // 0..63
    const int b = bh >> 3, h = bh & 7;
    const int k0 = blockIdx.x * 32, d0 = blockIdx.y * 32;
    const int c = threadIdx.x & 31, r = threadIdx.x >> 5;
#pragma unroll
    for (int i = 0; i < 4; i++) {
        int rr = r + i * 8;
        tile[rr][c] = vb[(size_t)(b * 1024 + k0 + rr) * 512 + h * 64 + d0 + c];
    }
    __syncthreads();
#pragma unroll
    for (int i = 0; i < 4; i++) {
        int rr = r + i * 8;
        vtg[(size_t)(bh * 64 + d0 + rr) * 1024 + k0 + c] = tile[c][rr];
    }
}

// ---------------------------------------------------------------------------
// Projection GEMM (verified R5): C = X(fp32) @ W(bf16^T) + bias -> bf16.
// ---------------------------------------------------------------------------
__global__ __launch_bounds__(256) void gemm_proj(
    const float* __restrict__ Q, const float* __restrict__ K,
    const u16* __restrict__ wt,
    const float* __restrict__ bq, const float* __restrict__ bk, const float* __restrict__ bv,
    u16* __restrict__ qb, u16* __restrict__ kb, u16* __restrict__ vb)
{
    __shared__ __align__(16) u16 lds_a[128 * 40];
    __shared__ __align__(16) u16 lds_b[128 * 40];

    const int z = blockIdx.z;
    const float* X = (z == 0) ? Q : K;
    const u16* Wt = wt + (size_t)z * 512 * 512;
    const float* bias = (z == 0) ? bq : (z == 1) ? bk : bv;
    u16* outb = (z == 0) ? qb : (z == 1) ? kb : vb;

    const int bm = blockIdx.y, bn = blockIdx.x;
    const int t = threadIdx.x;
    const int wave = t >> 6, lane = t & 63, quad = lane >> 4, lm = lane & 15;
    const int wm = wave >> 1, wn = wave & 1;

    f32x4 acc[4][4];
    const f32x4 zz = {0.f, 0.f, 0.f, 0.f};
#pragma unroll
    for (int i = 0; i < 4; i++)
#pragma unroll
        for (int j = 0; j < 4; j++) acc[i][j] = zz;

    for (int k0 = 0; k0 < 512; k0 += 32) {
#pragma unroll
        for (int i = 0; i < 2; i++) {
            int idx = t + i * 256;
            int r = idx >> 2, c = (idx & 3) * 8;
            const float* xp = &X[(size_t)(bm * 128 + r) * 512 + k0 + c];
            f32x4 a0 = *(const f32x4*)xp;
            f32x4 a1 = *(const f32x4*)(xp + 4);
            bf16x8 xv;
#pragma unroll
            for (int j = 0; j < 4; j++) { xv[j] = (short)f2bf(a0[j]); xv[4 + j] = (short)f2bf(a1[j]); }
            *(bf16x8*)&lds_a[r * 40 + c] = xv;
            *(bf16x8*)&lds_b[r * 40 + c] =
                *(const bf16x8*)&Wt[(size_t)(bn * 128 + r) * 512 + k0 + c];
        }
        __syncthreads();
        bf16x8 af[4], bfr[4];
#pragma unroll
        for (int mi = 0; mi < 4; mi++)
            af[mi] = *(const bf16x8*)&lds_a[(wm * 64 + mi * 16 + lm) * 40 + quad * 8];
#pragma unroll
        for (int ni = 0; ni < 4; ni++)
            bfr[ni] = *(const bf16x8*)&lds_b[(wn * 64 + ni * 16 + lm) * 40 + quad * 8];
#pragma unroll
        for (int mi = 0; mi < 4; mi++)
#pragma unroll
            for (int ni = 0; ni < 4; ni++)
                acc[mi][ni] = MFMA16(af[mi], bfr[ni], acc[mi][ni], 0, 0, 0);
        __syncthreads();
    }

#pragma unroll
    for (int mi = 0; mi < 4; mi++) {
#pragma unroll
        for (int ni = 0; ni < 4; ni++) {
            const int col = bn * 128 + wn * 64 + ni * 16 + lm;
            const float bv_ = bias[col];
#pragma unroll
            for (int r = 0; r < 4; r++) {
                const int row = bm * 128 + wm * 64 + mi * 16 + quad * 4 + r;
                outb[(size_t)row * 512 + col] = f2bf(acc[mi][ni][r] + bv_);
            }
        }
    }
}

// ---------------------------------------------------------------------------
// MLP GEMM (verified R5): Uf = resid(fp32) + relu(X(bf16) @ Wo^T + bo) -> fp32.
// ---------------------------------------------------------------------------
__global__ __launch_bounds__(256) void gemm_mlp(
    const u16* __restrict__ X, const u16* __restrict__ wt,
    const float* __restrict__ bo, const float* __restrict__ resid,
    float* __restrict__ outf)
{
    __shared__ __align__(16) u16 lds_a[128 * 40];
    __shared__ __align__(16) u16 lds_b[128 * 40];

    const u16* Wt = wt + (size_t)3 * 512 * 512;
    const int bm = blockIdx.y, bn = blockIdx.x;
    const int t = threadIdx.x;
    const int wave = t >> 6, lane = t & 63, quad = lane >> 4, lm = lane & 15;
    const int wm = wave >> 1, wn = wave & 1;

    f32x4 acc[4][4];
    const f32x4 zz = {0.f, 0.f, 0.f, 0.f};
#pragma unroll
    for (int i = 0; i < 4; i++)
#pragma unroll
        for (int j = 0; j < 4; j++) acc[i][j] = zz;

    for (int k0 = 0; k0 < 512; k0 += 32) {
#pragma unroll
        for (int i = 0; i < 2; i++) {
            int idx = t + i * 256;
            int r = idx >> 2, c = (idx & 3) * 8;
            *(bf16x8*)&lds_a[r * 40 + c] =
                *(const bf16x8*)&X[(size_t)(bm * 128 + r) * 512 + k0 + c];
            *(bf16x8*)&lds_b[r * 40 + c] =
                *(const bf16x8*)&Wt[(size_t)(bn * 128 + r) * 512 + k0 + c];
        }
        __syncthreads();
        bf16x8 af[4], bfr[4];
#pragma unroll
        for (int mi = 0; mi < 4; mi++)
            af[mi] = *(const bf16x8*)&lds_a[(wm * 64 + mi * 16 + lm) * 40 + quad * 8];
#pragma unroll
        for (int ni = 0; ni < 4; ni++)
            bfr[ni] = *(const bf16x8*)&lds_b[(wn * 64 + ni * 16 + lm) * 40 + quad * 8];
#pragma unroll
        for (int mi = 0; mi < 4; mi++)
#pragma unroll
            for (int ni = 0; ni < 4; ni++)
                acc[mi][ni] = MFMA16(af[mi], bfr[ni], acc[mi][ni], 0, 0, 0);
        __syncthreads();
    }

#pragma unroll
    for (int mi = 0; mi < 4; mi++) {
#pragma unroll
        for (int ni = 0; ni < 4; ni++) {
            const int col = bn * 128 + wn * 64 + ni * 16 + lm;
            const float bv_ = bo[col];
#pragma unroll
            for (int r = 0; r < 4; r++) {
                const int row = bm * 128 + wm * 64 + mi * 16 + quad * 4 + r;
                const size_t off = (size_t)row * 512 + col;
                outf[off] = resid[off] + fmaxf(acc[mi][ni][r] + bv_, 0.f);
            }
        }
    }
}

// ---------------------------------------------------------------------------
// Attention v7: block = (b, h, 64 q-rows), 4 waves x 16 q, grid 1024,
// 16 waves/CU. K/V staged in LDS (reg double-buffer), 2 barriers/tile.
// P REGISTER-RESIDENT: swapped QK^T (S^T = mfma(K,Q)) + RNE f2bf pack +
// permlane32/16 swaps build the PV A-frag in VGPRs -- no P LDS traffic.
// ---------------------------------------------------------------------------
__global__ __launch_bounds__(256, 4) void attn_kernel(
    const u16* __restrict__ qb, const u16* __restrict__ kb, const u16* __restrict__ vtg,
    const int* __restrict__ mask, float* __restrict__ O)
{
    __shared__ __align__(16) u16 k_tile[64 * 88];       // [key][d]
    __shared__ __align__(16) u16 vt[64 * 88];           // [d][key]

    // XCD swizzle: xcd = i&7; all 16 q-tiles of one (b,h) land on one XCD.
    const int i = blockIdx.x;
    const int s_ = i >> 3;
    const int bh = (i & 7) + 8 * (s_ >> 4);
    const int qt = s_ & 15;
    const int b = bh >> 3, h = bh & 7;

    const int t = threadIdx.x, wave = t >> 6, lane = t & 63;
    const int quad = lane >> 4, lm = lane & 15;
    const int qbase = qt * 64 + wave * 16;
    const size_t baseb = (size_t)b * 1024 * 512;
    const size_t vbase = (size_t)((b * 8 + h) * 64) * 1024;
    const int* mrow = &mask[b * 1024];

    // Q frags (B-operand of S^T = K.Q^T): col=lm -> q, k = ks*32+quad*8.
    bf16x8 aq[2];
#pragma unroll
    for (int ks = 0; ks < 2; ks++)
        aq[ks] = *(const bf16x8*)&qb[baseb +
            (size_t)(qbase + lm) * 512 + h * 64 + ks * 32 + quad * 8];

    float lsum_loc = 0.f;
    f32x4 oacc[4];
    const f32x4 zz = {0.f, 0.f, 0.f, 0.f};
#pragma unroll
    for (int c = 0; c < 4; c++) oacc[c] = zz;

    const float SC2 = 0.125f * 1.44269504088896341f; // (1/sqrt(64)) * log2(e)
    const int srow = t >> 2, scol = (t & 3) * 16;    // staging: 64 rows x 64

    const u16* kgp = &kb[baseb + (size_t)srow * 512 + h * 64 + scol];
    const u16* vgp = &vtg[vbase + (size_t)srow * 1024 + scol];

    bf16x8 kA0, kA1, vA0, vA1, kB0, kB1, vB0, vB1;

    auto load_t = [&](int kt, bf16x8& k0, bf16x8& k1, bf16x8& v0, bf16x8& v1) {
        const u16* kp = kgp + (size_t)kt * 64 * 512;
        k0 = *(const bf16x8*)kp;
        k1 = *(const bf16x8*)(kp + 8);
        const u16* vp = vgp + kt * 64;
        v0 = *(const bf16x8*)vp;
        v1 = *(const bf16x8*)(vp + 8);
    };
    auto store_t = [&](bf16x8 k0, bf16x8 k1, bf16x8 v0, bf16x8 v1) {
        *(bf16x8*)&k_tile[srow * 88 + scol]     = k0;
        *(bf16x8*)&k_tile[srow * 88 + scol + 8] = k1;
        *(bf16x8*)&vt[srow * 88 + scol]     = v0;
        *(bf16x8*)&vt[srow * 88 + scol + 8] = v1;
    };

    auto compute_t = [&](int kt) {
        const int keyg = kt * 64;
        // K frags (A-operand of S^T): row=lm -> key = n*16+lm. Same LDS
        // reads as the old B-operand path (identical lane layout).
        bf16x8 bk[4][2];
#pragma unroll
        for (int n = 0; n < 4; n++)
#pragma unroll
            for (int ks = 0; ks < 2; ks++)
                bk[n][ks] = *(const bf16x8*)&k_tile[(n * 16 + lm) * 88 + ks * 32 + quad * 8];

        // S^T: lane holds S^T(key = n*16+quad*4+r, q = lm), r=0..3.
        // Pack P to bf16 pairs, then permlane into PV A-frag key order:
        // lane quad tau needs keys ks*32 + tau*8 + {0..7}.
        u32 W[2][4];  // [ks][word]
#pragma unroll
        for (int half = 0; half < 2; half++) {
            u32 cP[2][2];  // [n within pair][key-pair t]
#pragma unroll
            for (int j = 0; j < 2; j++) {
                const int n = half * 2 + j;
                f32x4 S = zz;
                __builtin_amdgcn_s_setprio(1);
                S = MFMA16(bk[n][0], aq[0], S, 0, 0, 0);
                S = MFMA16(bk[n][1], aq[1], S, 0, 0, 0);
                __builtin_amdgcn_s_setprio(0);
                // mask bias at key = keyg + n*16 + quad*4 + r (int4, 16B)
                i32x4 m4 = *(const i32x4*)&mrow[keyg + n * 16 + quad * 4];
                float pr[4];
#pragma unroll
                for (int r = 0; r < 4; r++) {
                    pr[r] = __builtin_amdgcn_exp2f(
                        __builtin_fmaf(S[r], SC2, m4[r] ? 0.0f : -30000.0f));
                    lsum_loc += pr[r];
                }
                cP[j][0] = (u32)f2bf(pr[0]) | ((u32)f2bf(pr[1]) << 16);
                cP[j][1] = (u32)f2bf(pr[2]) | ((u32)f2bf(pr[3]) << 16);
            }
            // p32 then p16: a -> keys {8*tau + 2t,+1} (W[t]);
            //               b -> keys {8*tau + 4 + 2t,+1} (W[2+t]).
#pragma unroll
            for (int tt = 0; tt < 2; tt++) {
                u32 a = cP[0][tt], b = cP[1][tt];
                plane32_swap(a, b);
                plane16_swap(a, b);
                W[half][tt]     = a;
                W[half][2 + tt] = b;
            }
        }

        // PV: O += P.V^T  (same accumulation order as R13)
#pragma unroll
        for (int ks = 0; ks < 2; ks++) {
            u32x4 wv = {W[ks][0], W[ks][1], W[ks][2], W[ks][3]};
            bf16x8 ap = __builtin_bit_cast(bf16x8, wv);
            __builtin_amdgcn_s_setprio(1);
#pragma unroll
            for (int c = 0; c < 4; c++) {
                bf16x8 bv_ = *(const bf16x8*)&vt[(c * 16 + lm) * 88 + ks * 32 + quad * 8];
                oacc[c] = MFMA16(ap, bv_, oacc[c], 0, 0, 0);
            }
            __builtin_amdgcn_s_setprio(0);
        }
    };

    // prologue: tile 0 into regs
    load_t(0, kA0, kA1, vA0, vA1);

    for (int kt = 0; kt < 16; kt += 2) {
        store_t(kA0, kA1, vA0, vA1);          // vmcnt wait for tile kt here
        load_t(kt + 1, kB0, kB1, vB0, vB1);   // issue tile kt+1 (hidden)
        __syncthreads();
        compute_t(kt);
        __syncthreads();
        store_t(kB0, kB1, vB0, vB1);
        load_t((kt + 2) & 15, kA0, kA1, vA0, vA1); // &15: last iter dead-loads tile 0
        __syncthreads();
        compute_t(kt + 1);
        __syncthreads();
    }

    // lsum: lane partial covers q=lm, its quad's key slices. Reduce across
    // quads (xor16 + xor32) -> every lane holds L(q=lm); then fetch the
    // rows this lane's PV output owns (q = quad*4 + r).
    float s = lsum_loc;
    s += __shfl_xor(s, 16);
    s += __shfl_xor(s, 32);
    float lr[4];
#pragma unroll
    for (int r = 0; r < 4; r++) lr[r] = __shfl(s, quad * 4 + r);

    // epilogue: O = q + P.V / l  (fp32, coalesced over lm)
#pragma unroll
    for (int c = 0; c < 4; c++)
#pragma unroll
        for (int r = 0; r < 4; r++) {
            const int row = qbase + quad * 4 + r;
            const int d = h * 64 + c * 16 + lm;
            const size_t off = baseb + (size_t)row * 512 + d;
            O[off] = bf2f(qb[off]) + oacc[c][r] / lr[r];
        }
}

// ---------------------------------------------------------------------------
// Row LayerNorm over 512 (verified R5): fp32 in; optional bf16 + fp32 outs.
// ---------------------------------------------------------------------------
__global__ __launch_bounds__(256) void ln_kernel(
    const float* __restrict__ in, const float* __restrict__ g, const float* __restrict__ bsh,
    u16* __restrict__ outb, float* __restrict__ outf)
{
    const int row = blockIdx.x * 4 + (threadIdx.x >> 6);
    const int lane = threadIdx.x & 63;
    const float* x = in + (size_t)row * 512 + lane * 8;
    float v[8];
    *(f32x4*)&v[0] = *(const f32x4*)&x[0];
    *(f32x4*)&v[4] = *(const f32x4*)&x[4];
    float s = 0.f, sq = 0.f;
#pragma unroll
    for (int j = 0; j < 8; j++) { s += v[j]; sq += v[j] * v[j]; }
#pragma unroll
    for (int off = 1; off < 64; off <<= 1) {
        s += __shfl_xor(s, off);
        sq += __shfl_xor(sq, off);
    }
    const float mu = s * (1.f / 512.f);
    const float var = sq * (1.f / 512.f) - mu * mu;
    const float rs = rsqrtf(var + 1e-5f);
    float y[8];
#pragma unroll
    for (int j = 0; j < 8; j++) {
        int col = lane * 8 + j;
        y[j] = (v[j] - mu) * rs * g[col] + bsh[col];
    }
    if (outb != nullptr) {
        bf16x8 ov;
#pragma unroll
        for (int j = 0; j < 8; j++) ov[j] = (short)f2bf(y[j]);
        *(bf16x8*)&outb[(size_t)row * 512 + lane * 8] = ov;
    }
    if (outf != nullptr) {
        float* o = outf + (size_t)row * 512 + lane * 8;
        *(f32x4*)&o[0] = *(const f32x4*)&y[0];
        *(f32x4*)&o[4] = *(const f32x4*)&y[4];
    }
}

extern "C" void kernel_launch(void* const* d_in, const int* in_sizes, int n_in,
                              void* d_out, int out_size, void* d_ws, size_t ws_size,
                              hipStream_t stream) {
    const float* Q  = (const float*)d_in[0];
    const float* K  = (const float*)d_in[1];
    const int* mask = (const int*)d_in[2];
    const float* Wq = (const float*)d_in[3];
    const float* bq = (const float*)d_in[4];
    const float* Wk = (const float*)d_in[5];
    const float* bk = (const float*)d_in[6];
    const float* Wv = (const float*)d_in[7];
    const float* bv = (const float*)d_in[8];
    const float* Wo = (const float*)d_in[9];
    const float* bo = (const float*)d_in[10];
    const float* g0 = (const float*)d_in[11];
    const float* b0 = (const float*)d_in[12];
    const float* g1 = (const float*)d_in[13];
    const float* b1 = (const float*)d_in[14];
    float* out = (float*)d_out;

    char* ws = (char*)d_ws;
    const size_t MB = 1048576;
    u16*   wt  = (u16*)(ws);
    u16*   qb  = (u16*)(ws + 2 * MB);
    u16*   kb  = (u16*)(ws + 10 * MB);
    u16*   vtg = (u16*)(ws + 18 * MB);
    u16*   vb  = (u16*)(ws + 26 * MB);
    float* Of  = (float*)(ws + 26 * MB);  // overwrites vb (dead after transpose_v)
    u16*   O1b = (u16*)(ws + 2 * MB);     // reuse qb
    float* O1f = (float*)(ws + 10 * MB);  // reuse kb+vtg
    float* Uf  = (float*)(ws + 26 * MB);  // reuse Of

    transpose_w<<<dim3(16, 16, 4), 256, 0, stream>>>(Wq, Wk, Wv, Wo, wt);
    gemm_proj<<<dim3(4, 64, 3), 256, 0, stream>>>(Q, K, wt, bq, bk, bv, qb, kb, vb);
    transpose_v<<<dim3(32, 2, 64), 256, 0, stream>>>(vb, vtg);
    attn_kernel<<<1024, 256, 0, stream>>>(qb, kb, vtg, mask, Of);
    ln_kernel<<<2048, 256, 0, stream>>>(Of, g0, b0, O1b, O1f);
    gemm_mlp<<<dim3(4, 64, 1), 256, 0, stream>>>(O1b, wt, bo, O1f, Uf);
    ln_kernel<<<2048, 256, 0, stream>>>(Uf, g1, b1, nullptr, out);
}